// Round 1
// baseline (191.836 us; speedup 1.0000x reference)
//
#include <hip/hip_runtime.h>
#include <hip/hip_bf16.h>
#include <math.h>

#define H 2048
#define W 4096
#define NPIX (H * W)
#define KSEL 4194303u   // (N-1)/2, 0-indexed order statistic for lower median
#define TS 32
#define XS 40   // TS + 2*4 (sobel halo 1 + gauss halo 3)
#define PS 38   // TS + 2*3 (gauss halo)

__device__ __forceinline__ unsigned fmap(float f) {
    unsigned u = __float_as_uint(f);
    return (u & 0x80000000u) ? ~u : (u | 0x80000000u);
}

// Pass A: fused sobel + products + separable 7x7 gaussian + harris response.
// Writes r, accumulates top-8-bit histogram.
__global__ __launch_bounds__(256) void k_response(const float* __restrict__ x,
                                                  const float* __restrict__ gw,
                                                  float* __restrict__ r,
                                                  unsigned* __restrict__ hist1) {
    __shared__ float sx[XS][XS];
    __shared__ float p0[PS][PS], p1[PS][PS], p2[PS][PS];
    __shared__ float h0[PS][TS], h1[PS][TS], h2[PS][TS];
    __shared__ unsigned lh[256];
    __shared__ float hw[7], vw[7];

    int t = threadIdx.x;
    int bx = blockIdx.x & (W / TS - 1);
    int by = blockIdx.x / (W / TS);
    int ty0 = by * TS, tx0 = bx * TS;

    if (t < 7) {
        hw[t] = gw[21 + t];            // g2[3][b]
        vw[t] = gw[t * 7 + 3] / gw[24]; // g2[a][3] / g2[3][3]
    }
    lh[t] = 0;

    // load x tile with halo 4, zero-padded
    for (int i = t; i < XS * XS; i += 256) {
        int iy = i / XS, ix = i % XS;
        int gy = ty0 - 4 + iy, gx = tx0 - 4 + ix;
        float v = 0.f;
        if (gy >= 0 && gy < H && gx >= 0 && gx < W) v = x[gy * W + gx];
        sx[iy][ix] = v;
    }
    __syncthreads();

    // sobel + products on extended region (halo 3); zero outside image
    for (int i = t; i < PS * PS; i += 256) {
        int iy = i / PS, ix = i % PS;
        int gy = ty0 - 3 + iy, gx = tx0 - 3 + ix;
        float a = 0.f, b = 0.f, c = 0.f;
        if (gy >= 0 && gy < H && gx >= 0 && gx < W) {
            float ixv = (sx[iy][ix + 2] - sx[iy][ix])
                      + 2.f * (sx[iy + 1][ix + 2] - sx[iy + 1][ix])
                      + (sx[iy + 2][ix + 2] - sx[iy + 2][ix]);
            float iyv = (sx[iy + 2][ix] - sx[iy][ix])
                      + 2.f * (sx[iy + 2][ix + 1] - sx[iy][ix + 1])
                      + (sx[iy + 2][ix + 2] - sx[iy][ix + 2]);
            a = ixv * ixv; b = iyv * iyv; c = ixv * iyv;
        }
        p0[iy][ix] = a; p1[iy][ix] = b; p2[iy][ix] = c;
    }
    __syncthreads();

    // horizontal gaussian
    for (int i = t; i < PS * TS; i += 256) {
        int iy = i / TS, jj = i % TS;
        float s0 = 0.f, s1 = 0.f, s2 = 0.f;
#pragma unroll
        for (int b = 0; b < 7; ++b) {
            float w = hw[b];
            s0 += w * p0[iy][jj + b];
            s1 += w * p1[iy][jj + b];
            s2 += w * p2[iy][jj + b];
        }
        h0[iy][jj] = s0; h1[iy][jj] = s1; h2[iy][jj] = s2;
    }
    __syncthreads();

    // vertical gaussian + response + local histogram
    for (int i = t; i < TS * TS; i += 256) {
        int ii = i / TS, jj = i % TS;
        float sxx = 0.f, syy = 0.f, sxy = 0.f;
#pragma unroll
        for (int a = 0; a < 7; ++a) {
            float w = vw[a];
            sxx += w * h0[ii + a][jj];
            syy += w * h1[ii + a][jj];
            sxy += w * h2[ii + a][jj];
        }
        float tr = sxx + syy;
        float rv = sxx * syy - sxy * sxy - 0.05f * tr * tr;
        r[(ty0 + ii) * W + tx0 + jj] = rv;
        atomicAdd(&lh[fmap(rv) >> 24], 1u);
    }
    __syncthreads();
    if (lh[t]) atomicAdd(&hist1[t], lh[t]);
}

// scan 256 bins, find bin containing rank; write bin + remaining rank to sel
__global__ __launch_bounds__(256) void k_scan256(const unsigned* __restrict__ hist,
                                                 unsigned* __restrict__ sel,
                                                 int in_rank_idx, int out_base) {
    __shared__ unsigned s[256];
    int t = threadIdx.x;
    unsigned c = hist[t];
    s[t] = c;
    __syncthreads();
    for (int off = 1; off < 256; off <<= 1) {
        unsigned v = (t >= off) ? s[t - off] : 0u;
        __syncthreads();
        s[t] += v;
        __syncthreads();
    }
    unsigned k = (in_rank_idx < 0) ? KSEL : sel[in_rank_idx];
    unsigned cumb = s[t] - c;
    if (k >= cumb && k < s[t]) {
        sel[out_base] = (unsigned)t;
        sel[out_base + 1] = k - cumb;
    }
}

// histogram bits 16..23 among elements whose top-8 matches sel[0]
__global__ __launch_bounds__(256) void k_hist2(const float* __restrict__ r,
                                               const unsigned* __restrict__ sel,
                                               unsigned* __restrict__ hist2) {
    __shared__ unsigned lh[256];
    lh[threadIdx.x] = 0;
    __syncthreads();
    unsigned b1 = sel[0];
    int idx = blockIdx.x * blockDim.x + threadIdx.x;
    int stride = gridDim.x * blockDim.x;
    const float4* r4 = (const float4*)r;
    for (int i = idx; i < NPIX / 4; i += stride) {
        float4 v = r4[i];
        unsigned u;
        u = fmap(v.x); if ((u >> 24) == b1) atomicAdd(&lh[(u >> 16) & 0xFF], 1u);
        u = fmap(v.y); if ((u >> 24) == b1) atomicAdd(&lh[(u >> 16) & 0xFF], 1u);
        u = fmap(v.z); if ((u >> 24) == b1) atomicAdd(&lh[(u >> 16) & 0xFF], 1u);
        u = fmap(v.w); if ((u >> 24) == b1) atomicAdd(&lh[(u >> 16) & 0xFF], 1u);
    }
    __syncthreads();
    if (lh[threadIdx.x]) atomicAdd(&hist2[threadIdx.x], lh[threadIdx.x]);
}

// histogram low 16 bits among elements whose top-16 matches (sel[0]<<8)|sel[2]
__global__ __launch_bounds__(256) void k_hist3(const float* __restrict__ r,
                                               const unsigned* __restrict__ sel,
                                               unsigned* __restrict__ hist3) {
    unsigned top16 = (sel[0] << 8) | sel[2];
    int idx = blockIdx.x * blockDim.x + threadIdx.x;
    int stride = gridDim.x * blockDim.x;
    const float4* r4 = (const float4*)r;
    for (int i = idx; i < NPIX / 4; i += stride) {
        float4 v = r4[i];
        unsigned u;
        u = fmap(v.x); if ((u >> 16) == top16) atomicAdd(&hist3[u & 0xFFFF], 1u);
        u = fmap(v.y); if ((u >> 16) == top16) atomicAdd(&hist3[u & 0xFFFF], 1u);
        u = fmap(v.z); if ((u >> 16) == top16) atomicAdd(&hist3[u & 0xFFFF], 1u);
        u = fmap(v.w); if ((u >> 16) == top16) atomicAdd(&hist3[u & 0xFFFF], 1u);
    }
}

// scan 64K bins (256 threads x 256-bin chunks), resolve final median value
__global__ __launch_bounds__(256) void k_scan64k(const unsigned* __restrict__ hist3,
                                                 unsigned* __restrict__ sel) {
    __shared__ unsigned s[256];
    int t = threadIdx.x;
    unsigned sum = 0;
    for (int i = 0; i < 256; ++i) sum += hist3[t * 256 + i];
    s[t] = sum;
    __syncthreads();
    for (int off = 1; off < 256; off <<= 1) {
        unsigned v = (t >= off) ? s[t - off] : 0u;
        __syncthreads();
        s[t] += v;
        __syncthreads();
    }
    unsigned k = sel[3];
    unsigned cumb = s[t] - sum;
    if (k >= cumb && k < s[t]) {
        unsigned rem = k - cumb;
        unsigned cum = 0, b3 = 0;
        for (int i = 0; i < 256; ++i) {
            unsigned c = hist3[t * 256 + i];
            if (rem < cum + c) { b3 = (unsigned)(t * 256 + i); break; }
            cum += c;
        }
        unsigned med_u = (sel[0] << 24) | (sel[2] << 16) | b3;
        unsigned bits = (med_u & 0x80000000u) ? (med_u & 0x7FFFFFFFu) : ~med_u;
        ((float*)sel)[4] = __uint_as_float(bits);
    }
}

// Pass D: threshold + separable 7x7 maxpool + NMS mask
__global__ __launch_bounds__(256) void k_final(const float* __restrict__ r,
                                               const unsigned* __restrict__ sel,
                                               float* __restrict__ out) {
    __shared__ float rt[PS][PS];
    __shared__ float th[PS][PS];
    __shared__ float hm[PS][TS];
    float med = ((const float*)sel)[4];
    int t = threadIdx.x;
    int bx = blockIdx.x & (W / TS - 1);
    int by = blockIdx.x / (W / TS);
    int ty0 = by * TS, tx0 = bx * TS;

    for (int i = t; i < PS * PS; i += 256) {
        int iy = i / PS, ix = i % PS;
        int gy = ty0 - 3 + iy, gx = tx0 - 3 + ix;
        float v = -INFINITY, tv = -INFINITY;
        if (gy >= 0 && gy < H && gx >= 0 && gx < W) {
            v = r[gy * W + gx];
            tv = (v > med) ? v : 0.f;
        }
        rt[iy][ix] = v;
        th[iy][ix] = tv;
    }
    __syncthreads();

    for (int i = t; i < PS * TS; i += 256) {
        int iy = i / TS, jj = i % TS;
        float m = th[iy][jj];
#pragma unroll
        for (int b = 1; b < 7; ++b) m = fmaxf(m, th[iy][jj + b]);
        hm[iy][jj] = m;
    }
    __syncthreads();

    for (int i = t; i < TS * TS; i += 256) {
        int ii = i / TS, jj = i % TS;
        float m = hm[ii][jj];
#pragma unroll
        for (int a = 1; a < 7; ++a) m = fmaxf(m, hm[ii + a][jj]);
        float rv = rt[ii + 3][jj + 3];
        float tv = th[ii + 3][jj + 3];
        out[(ty0 + ii) * W + tx0 + jj] = (m == tv) ? rv : 0.f;
    }
}

extern "C" void kernel_launch(void* const* d_in, const int* in_sizes, int n_in,
                              void* d_out, int out_size, void* d_ws, size_t ws_size,
                              hipStream_t stream) {
    const float* x = (const float*)d_in[0];
    const float* gw = (const float*)d_in[2];
    float* out = (float*)d_out;

    char* ws = (char*)d_ws;
    float* r = (float*)ws;
    unsigned* hist1 = (unsigned*)(ws + (size_t)NPIX * 4);
    unsigned* hist2 = hist1 + 256;
    unsigned* hist3 = hist2 + 256;
    unsigned* sel = hist3 + 65536;

    hipMemsetAsync(hist1, 0, (256 + 256 + 65536 + 8) * sizeof(unsigned), stream);

    int nblk = (H / TS) * (W / TS); // 64 * 128 = 8192
    k_response<<<nblk, 256, 0, stream>>>(x, gw, r, hist1);
    k_scan256<<<1, 256, 0, stream>>>(hist1, sel, -1, 0);
    k_hist2<<<1024, 256, 0, stream>>>(r, sel, hist2);
    k_scan256<<<1, 256, 0, stream>>>(hist2, sel, 1, 2);
    k_hist3<<<1024, 256, 0, stream>>>(r, sel, hist3);
    k_scan64k<<<1, 256, 0, stream>>>(hist3, sel);
    k_final<<<nblk, 256, 0, stream>>>(r, sel, out);
}

// Round 2
// 186.120 us; speedup vs baseline: 1.0307x; 1.0307x over previous
//
#include <hip/hip_runtime.h>
#include <hip/hip_bf16.h>
#include <math.h>

#define H 2048
#define W 4096
#define NPIX (H * W)
#define KSEL 4194303u   // (N-1)/2, 0-indexed order statistic for lower median
#define TS 32
#define XS 40   // TS + 2*4 (sobel halo 1 + gauss halo 3)
#define PS 38   // TS + 2*3 (gauss halo)
#define NT 512  // threads per block for tile kernels

__device__ __forceinline__ unsigned fmap(float f) {
    unsigned u = __float_as_uint(f);
    return (u & 0x80000000u) ? ~u : (u | 0x80000000u);
}

// Pass A: fused sobel + products + separable 7x7 gaussian + harris response.
// Writes r, accumulates top-8-bit histogram.
__global__ __launch_bounds__(NT) void k_response(const float* __restrict__ x,
                                                 const float* __restrict__ gw,
                                                 float* __restrict__ r,
                                                 unsigned* __restrict__ hist1) {
    __shared__ float sx[XS][XS + 1];
    __shared__ float2 gxy[PS][PS];           // (ix, iy) gradients
    __shared__ float h0[PS][TS], h1[PS][TS], h2[PS][TS];
    __shared__ unsigned lh[256];
    __shared__ float hw[7], vw[7];

    int t = threadIdx.x;
    int bx = blockIdx.x & (W / TS - 1);
    int by = blockIdx.x / (W / TS);
    int ty0 = by * TS, tx0 = bx * TS;

    if (t < 7) {
        hw[t] = gw[21 + t];             // g2[3][b]
        vw[t] = gw[t * 7 + 3] / gw[24]; // g2[a][3] / g2[3][3]
    }
    if (t < 256) lh[t] = 0;

    // load x tile with halo 4, zero-padded
    for (int i = t; i < XS * XS; i += NT) {
        int iy = i / XS, ix = i % XS;
        int gy = ty0 - 4 + iy, gx = tx0 - 4 + ix;
        float v = 0.f;
        if (gy >= 0 && gy < H && gx >= 0 && gx < W) v = x[gy * W + gx];
        sx[iy][ix] = v;
    }
    __syncthreads();

    // sobel gradients on extended region (halo 3); zero outside image
    for (int i = t; i < PS * PS; i += NT) {
        int iy = i / PS, ix = i % PS;
        int gy = ty0 - 3 + iy, gx = tx0 - 3 + ix;
        float a = 0.f, b = 0.f;
        if (gy >= 0 && gy < H && gx >= 0 && gx < W) {
            a = (sx[iy][ix + 2] - sx[iy][ix])
              + 2.f * (sx[iy + 1][ix + 2] - sx[iy + 1][ix])
              + (sx[iy + 2][ix + 2] - sx[iy + 2][ix]);
            b = (sx[iy + 2][ix] - sx[iy][ix])
              + 2.f * (sx[iy + 2][ix + 1] - sx[iy][ix + 1])
              + (sx[iy + 2][ix + 2] - sx[iy][ix + 2]);
        }
        gxy[iy][ix] = make_float2(a, b);
    }
    __syncthreads();

    // horizontal gaussian of products (products computed on the fly)
    for (int i = t; i < PS * TS; i += NT) {
        int iy = i / TS, jj = i % TS;
        float s0 = 0.f, s1 = 0.f, s2 = 0.f;
#pragma unroll
        for (int b = 0; b < 7; ++b) {
            float w = hw[b];
            float2 g = gxy[iy][jj + b];
            s0 += w * (g.x * g.x);
            s1 += w * (g.y * g.y);
            s2 += w * (g.x * g.y);
        }
        h0[iy][jj] = s0; h1[iy][jj] = s1; h2[iy][jj] = s2;
    }
    __syncthreads();

    // vertical gaussian + response + local histogram
    for (int i = t; i < TS * TS; i += NT) {
        int ii = i / TS, jj = i % TS;
        float sxx = 0.f, syy = 0.f, sxy = 0.f;
#pragma unroll
        for (int a = 0; a < 7; ++a) {
            float w = vw[a];
            sxx += w * h0[ii + a][jj];
            syy += w * h1[ii + a][jj];
            sxy += w * h2[ii + a][jj];
        }
        float tr = sxx + syy;
        float rv = sxx * syy - sxy * sxy - 0.05f * tr * tr;
        r[(ty0 + ii) * W + tx0 + jj] = rv;
        atomicAdd(&lh[fmap(rv) >> 24], 1u);
    }
    __syncthreads();
    if (t < 256 && lh[t]) atomicAdd(&hist1[t], lh[t]);
}

// scan 256 bins, find bin containing rank; write bin + remaining rank to sel
__global__ __launch_bounds__(256) void k_scan256(const unsigned* __restrict__ hist,
                                                 unsigned* __restrict__ sel,
                                                 int in_rank_idx, int out_base) {
    __shared__ unsigned s[256];
    int t = threadIdx.x;
    unsigned c = hist[t];
    s[t] = c;
    __syncthreads();
    for (int off = 1; off < 256; off <<= 1) {
        unsigned v = (t >= off) ? s[t - off] : 0u;
        __syncthreads();
        s[t] += v;
        __syncthreads();
    }
    unsigned k = (in_rank_idx < 0) ? KSEL : sel[in_rank_idx];
    unsigned cumb = s[t] - c;
    if (k >= cumb && k < s[t]) {
        sel[out_base] = (unsigned)t;
        sel[out_base + 1] = k - cumb;
    }
}

// histogram bits 16..23 among elements whose top-8 matches sel[0]
__global__ __launch_bounds__(256) void k_hist2(const float* __restrict__ r,
                                               const unsigned* __restrict__ sel,
                                               unsigned* __restrict__ hist2) {
    __shared__ unsigned lh[256];
    lh[threadIdx.x] = 0;
    __syncthreads();
    unsigned b1 = sel[0];
    int idx = blockIdx.x * blockDim.x + threadIdx.x;
    int stride = gridDim.x * blockDim.x;
    const float4* r4 = (const float4*)r;
    for (int i = idx; i < NPIX / 4; i += stride) {
        float4 v = r4[i];
        unsigned u;
        u = fmap(v.x); if ((u >> 24) == b1) atomicAdd(&lh[(u >> 16) & 0xFF], 1u);
        u = fmap(v.y); if ((u >> 24) == b1) atomicAdd(&lh[(u >> 16) & 0xFF], 1u);
        u = fmap(v.z); if ((u >> 24) == b1) atomicAdd(&lh[(u >> 16) & 0xFF], 1u);
        u = fmap(v.w); if ((u >> 24) == b1) atomicAdd(&lh[(u >> 16) & 0xFF], 1u);
    }
    __syncthreads();
    if (lh[threadIdx.x]) atomicAdd(&hist2[threadIdx.x], lh[threadIdx.x]);
}

// histogram low 16 bits among elements whose top-16 matches (sel[0]<<8)|sel[2]
__global__ __launch_bounds__(256) void k_hist3(const float* __restrict__ r,
                                               const unsigned* __restrict__ sel,
                                               unsigned* __restrict__ hist3) {
    unsigned top16 = (sel[0] << 8) | sel[2];
    int idx = blockIdx.x * blockDim.x + threadIdx.x;
    int stride = gridDim.x * blockDim.x;
    const float4* r4 = (const float4*)r;
    for (int i = idx; i < NPIX / 4; i += stride) {
        float4 v = r4[i];
        unsigned u;
        u = fmap(v.x); if ((u >> 16) == top16) atomicAdd(&hist3[u & 0xFFFF], 1u);
        u = fmap(v.y); if ((u >> 16) == top16) atomicAdd(&hist3[u & 0xFFFF], 1u);
        u = fmap(v.z); if ((u >> 16) == top16) atomicAdd(&hist3[u & 0xFFFF], 1u);
        u = fmap(v.w); if ((u >> 16) == top16) atomicAdd(&hist3[u & 0xFFFF], 1u);
    }
}

// scan 64K bins (256 threads x 256-bin chunks), resolve final median value
__global__ __launch_bounds__(256) void k_scan64k(const unsigned* __restrict__ hist3,
                                                 unsigned* __restrict__ sel) {
    __shared__ unsigned s[256];
    int t = threadIdx.x;
    unsigned sum = 0;
    for (int i = 0; i < 256; ++i) sum += hist3[t * 256 + i];
    s[t] = sum;
    __syncthreads();
    for (int off = 1; off < 256; off <<= 1) {
        unsigned v = (t >= off) ? s[t - off] : 0u;
        __syncthreads();
        s[t] += v;
        __syncthreads();
    }
    unsigned k = sel[3];
    unsigned cumb = s[t] - sum;
    if (k >= cumb && k < s[t]) {
        unsigned rem = k - cumb;
        unsigned cum = 0, b3 = 0;
        for (int i = 0; i < 256; ++i) {
            unsigned c = hist3[t * 256 + i];
            if (rem < cum + c) { b3 = (unsigned)(t * 256 + i); break; }
            cum += c;
        }
        unsigned med_u = (sel[0] << 24) | (sel[2] << 16) | b3;
        unsigned bits = (med_u & 0x80000000u) ? (med_u & 0x7FFFFFFFu) : ~med_u;
        ((float*)sel)[4] = __uint_as_float(bits);
    }
}

// Pass D: threshold + separable 7x7 maxpool + NMS mask
__global__ __launch_bounds__(NT) void k_final(const float* __restrict__ r,
                                              const unsigned* __restrict__ sel,
                                              float* __restrict__ out) {
    __shared__ float rt[PS][PS];
    __shared__ float th[PS][PS];
    __shared__ float hm[PS][TS];
    float med = ((const float*)sel)[4];
    int t = threadIdx.x;
    int bx = blockIdx.x & (W / TS - 1);
    int by = blockIdx.x / (W / TS);
    int ty0 = by * TS, tx0 = bx * TS;

    for (int i = t; i < PS * PS; i += NT) {
        int iy = i / PS, ix = i % PS;
        int gy = ty0 - 3 + iy, gx = tx0 - 3 + ix;
        float v = -INFINITY, tv = -INFINITY;
        if (gy >= 0 && gy < H && gx >= 0 && gx < W) {
            v = r[gy * W + gx];
            tv = (v > med) ? v : 0.f;
        }
        rt[iy][ix] = v;
        th[iy][ix] = tv;
    }
    __syncthreads();

    for (int i = t; i < PS * TS; i += NT) {
        int iy = i / TS, jj = i % TS;
        float m = th[iy][jj];
#pragma unroll
        for (int b = 1; b < 7; ++b) m = fmaxf(m, th[iy][jj + b]);
        hm[iy][jj] = m;
    }
    __syncthreads();

    for (int i = t; i < TS * TS; i += NT) {
        int ii = i / TS, jj = i % TS;
        float m = hm[ii][jj];
#pragma unroll
        for (int a = 1; a < 7; ++a) m = fmaxf(m, hm[ii + a][jj]);
        float rv = rt[ii + 3][jj + 3];
        float tv = th[ii + 3][jj + 3];
        out[(ty0 + ii) * W + tx0 + jj] = (m == tv) ? rv : 0.f;
    }
}

extern "C" void kernel_launch(void* const* d_in, const int* in_sizes, int n_in,
                              void* d_out, int out_size, void* d_ws, size_t ws_size,
                              hipStream_t stream) {
    const float* x = (const float*)d_in[0];
    const float* gw = (const float*)d_in[2];
    float* out = (float*)d_out;

    char* ws = (char*)d_ws;
    float* r = (float*)ws;
    unsigned* hist1 = (unsigned*)(ws + (size_t)NPIX * 4);
    unsigned* hist2 = hist1 + 256;
    unsigned* hist3 = hist2 + 256;
    unsigned* sel = hist3 + 65536;

    hipMemsetAsync(hist1, 0, (256 + 256 + 65536 + 8) * sizeof(unsigned), stream);

    int nblk = (H / TS) * (W / TS); // 64 * 128 = 8192
    k_response<<<nblk, NT, 0, stream>>>(x, gw, r, hist1);
    k_scan256<<<1, 256, 0, stream>>>(hist1, sel, -1, 0);
    k_hist2<<<1024, 256, 0, stream>>>(r, sel, hist2);
    k_scan256<<<1, 256, 0, stream>>>(hist2, sel, 1, 2);
    k_hist3<<<1024, 256, 0, stream>>>(r, sel, hist3);
    k_scan64k<<<1, 256, 0, stream>>>(hist3, sel);
    k_final<<<nblk, NT, 0, stream>>>(r, sel, out);
}

// Round 3
// 140.739 us; speedup vs baseline: 1.3631x; 1.3225x over previous
//
#include <hip/hip_runtime.h>
#include <hip/hip_bf16.h>
#include <math.h>

#define H 2048
#define W 4096
#define NPIX (H * W)
#define KSEL 4194303u   // (N-1)/2, 0-indexed order statistic for lower median
#define NT 512          // threads per tile block: (16 x 32)
#define TSX 64          // tile width
#define TSY 32          // tile height
#define NBX (W / TSX)   // 64
#define NBY (H / TSY)   // 64

__device__ __forceinline__ unsigned fmap(float f) {
    unsigned u = __float_as_uint(f);
    return (u & 0x80000000u) ? ~u : (u | 0x80000000u);
}
__device__ __forceinline__ float4 ld4s(const float* p) { return *(const float4*)p; }
__device__ __forceinline__ void st4s(float* p, float4 v) { *(float4*)p = v; }

// ---------------- Pass A: fused sobel + products + separable 7x7 gaussian ----------------
// LDS layout (floats):
//   gx : 0     .. 2736   (38 rows x 72)
//   gy : 2736  .. 5472
//   sx : 5472  .. 8512   (40 rows x 76)   [dead after sobel]
//   h0 : 5472  .. 8056   (38 rows x 68)   [overlays sx]
//   h1 : 8056  .. 10640
//   h2 : 10640 .. 13224
//   lh : 13224 .. 13480  (256 uints)
#define SMF 13480
#define SXA(r,c) smem[5472 + (r)*76 + (c)]
#define GXA(r,c) smem[(r)*72 + (c)]
#define GYA(r,c) smem[2736 + (r)*72 + (c)]
#define H0A(r,c) smem[5472 + (r)*68 + (c)]
#define H1A(r,c) smem[8056 + (r)*68 + (c)]
#define H2A(r,c) smem[10640 + (r)*68 + (c)]

__global__ __launch_bounds__(NT) void k_response(const float* __restrict__ x,
                                                 const float* __restrict__ gw,
                                                 float* __restrict__ r,
                                                 unsigned* __restrict__ hist1) {
    __shared__ float smem[SMF];
    unsigned* lh = (unsigned*)&smem[13224];

    int tl = threadIdx.x;
    int bx = blockIdx.x & (NBX - 1);
    int by = blockIdx.x >> 6;
    int tx0 = bx * TSX, ty0 = by * TSY;

    // weights in registers (same arithmetic as R1: hw=g2[3][b], vw=g2[a][3]/g2[3][3])
    float hwr[7], vwr[7];
    float g33 = gw[24];
#pragma unroll
    for (int b = 0; b < 7; ++b) hwr[b] = gw[21 + b];
#pragma unroll
    for (int a = 0; a < 7; ++a) vwr[a] = gw[a * 7 + 3] / g33;

    if (tl < 256) lh[tl] = 0;

    // ---- load x tile: rows ty0-4..ty0+35 (40), cols tx0-4..tx0+67 (72 = 18 groups) ----
#pragma unroll
    for (int it = 0; it < 2; ++it) {
        int task = tl + it * NT;
        if (task < 720) {
            int row = task / 18, g = task - row * 18;
            int gy = ty0 - 4 + row;
            int gx0 = tx0 - 4 + 4 * g;
            float4 v = make_float4(0.f, 0.f, 0.f, 0.f);
            if ((unsigned)gy < H) {
                if ((unsigned)gx0 <= (unsigned)(W - 4)) {
                    v = *(const float4*)&x[(size_t)gy * W + gx0];
                } else {
                    float* vv = (float*)&v;
#pragma unroll
                    for (int k = 0; k < 4; ++k) {
                        int c = gx0 + k;
                        if ((unsigned)c < W) vv[k] = x[(size_t)gy * W + c];
                    }
                }
            }
            st4s(&SXA(row, 4 * g), v);
        }
    }
    __syncthreads();

    // ---- sobel gradients: 38 rows x 18 groups (72 slots, idx q=4g+k <-> img col tx0+q-3) ----
#pragma unroll
    for (int it = 0; it < 2; ++it) {
        int task = tl + it * NT;
        if (task < 684) {
            int row = task / 18, g = task - row * 18;
            int base = 4 * g;
            float w0[8], w1[8], w2[8];
            {
                float4 t0 = ld4s(&SXA(row, base)), t1 = ld4s(&SXA(row, base + 4));
                w0[0]=t0.x; w0[1]=t0.y; w0[2]=t0.z; w0[3]=t0.w; w0[4]=t1.x; w0[5]=t1.y; w0[6]=t1.z; w0[7]=t1.w;
                t0 = ld4s(&SXA(row + 1, base)); t1 = ld4s(&SXA(row + 1, base + 4));
                w1[0]=t0.x; w1[1]=t0.y; w1[2]=t0.z; w1[3]=t0.w; w1[4]=t1.x; w1[5]=t1.y; w1[6]=t1.z; w1[7]=t1.w;
                t0 = ld4s(&SXA(row + 2, base)); t1 = ld4s(&SXA(row + 2, base + 4));
                w2[0]=t0.x; w2[1]=t0.y; w2[2]=t0.z; w2[3]=t0.w; w2[4]=t1.x; w2[5]=t1.y; w2[6]=t1.z; w2[7]=t1.w;
            }
            int rowOK = ((unsigned)(ty0 - 3 + row) < H);
            float4 gxv, gyv;
            float* pgx = (float*)&gxv;
            float* pgy = (float*)&gyv;
#pragma unroll
            for (int k = 0; k < 4; ++k) {
                float ixv = (w0[k + 2] - w0[k]) + 2.f * (w1[k + 2] - w1[k]) + (w2[k + 2] - w2[k]);
                float iyv = (w2[k] - w0[k]) + 2.f * (w2[k + 1] - w0[k + 1]) + (w2[k + 2] - w0[k + 2]);
                int gc = tx0 + base + k - 3;
                bool ok = rowOK && ((unsigned)gc < W);
                pgx[k] = ok ? ixv : 0.f;
                pgy[k] = ok ? iyv : 0.f;
            }
            st4s(&GXA(row, base), gxv);
            st4s(&GYA(row, base), gyv);
        }
    }
    __syncthreads();

    // ---- horizontal gaussian of products (on the fly): 38 rows x 16 groups ----
#pragma unroll
    for (int it = 0; it < 2; ++it) {
        int task = tl + it * NT;
        if (task < 608) {
            int row = task >> 4, c0 = (task & 15) * 4;
            float wgx[12], wgy[12];
            {
                float4 t0 = ld4s(&GXA(row, c0)), t1 = ld4s(&GXA(row, c0 + 4)), t2 = ld4s(&GXA(row, c0 + 8));
                wgx[0]=t0.x; wgx[1]=t0.y; wgx[2]=t0.z; wgx[3]=t0.w; wgx[4]=t1.x; wgx[5]=t1.y; wgx[6]=t1.z; wgx[7]=t1.w;
                wgx[8]=t2.x; wgx[9]=t2.y; wgx[10]=t2.z; wgx[11]=t2.w;
                t0 = ld4s(&GYA(row, c0)); t1 = ld4s(&GYA(row, c0 + 4)); t2 = ld4s(&GYA(row, c0 + 8));
                wgy[0]=t0.x; wgy[1]=t0.y; wgy[2]=t0.z; wgy[3]=t0.w; wgy[4]=t1.x; wgy[5]=t1.y; wgy[6]=t1.z; wgy[7]=t1.w;
                wgy[8]=t2.x; wgy[9]=t2.y; wgy[10]=t2.z; wgy[11]=t2.w;
            }
            float px[10], py[10], pxy[10];
#pragma unroll
            for (int i = 0; i < 10; ++i) {
                px[i] = wgx[i] * wgx[i];
                py[i] = wgy[i] * wgy[i];
                pxy[i] = wgx[i] * wgy[i];
            }
            float4 s0, s1, s2;
            float* q0 = (float*)&s0; float* q1 = (float*)&s1; float* q2 = (float*)&s2;
#pragma unroll
            for (int k = 0; k < 4; ++k) {
                float a0 = 0.f, a1 = 0.f, a2 = 0.f;
#pragma unroll
                for (int b = 0; b < 7; ++b) {
                    float w = hwr[b];
                    a0 += w * px[k + b];
                    a1 += w * py[k + b];
                    a2 += w * pxy[k + b];
                }
                q0[k] = a0; q1[k] = a1; q2[k] = a2;
            }
            st4s(&H0A(row, c0), s0);
            st4s(&H1A(row, c0), s1);
            st4s(&H2A(row, c0), s2);
        }
    }
    __syncthreads();

    // ---- vertical gaussian + response + histogram: 32 rows x 16 groups = 512 ----
    {
        int ii = tl >> 4, c0 = (tl & 15) * 4;
        float4 a0 = make_float4(0.f, 0.f, 0.f, 0.f), a1 = a0, a2 = a0;
#pragma unroll
        for (int a = 0; a < 7; ++a) {
            float w = vwr[a];
            float4 h0v = ld4s(&H0A(ii + a, c0));
            float4 h1v = ld4s(&H1A(ii + a, c0));
            float4 h2v = ld4s(&H2A(ii + a, c0));
            a0.x += w * h0v.x; a0.y += w * h0v.y; a0.z += w * h0v.z; a0.w += w * h0v.w;
            a1.x += w * h1v.x; a1.y += w * h1v.y; a1.z += w * h1v.z; a1.w += w * h1v.w;
            a2.x += w * h2v.x; a2.y += w * h2v.y; a2.z += w * h2v.z; a2.w += w * h2v.w;
        }
        float* sxx = (float*)&a0; float* syy = (float*)&a1; float* sxy = (float*)&a2;
        float4 rv4;
        float* prv = (float*)&rv4;
#pragma unroll
        for (int k = 0; k < 4; ++k) {
            float tr = sxx[k] + syy[k];
            float rv = sxx[k] * syy[k] - sxy[k] * sxy[k] - 0.05f * tr * tr;
            prv[k] = rv;
        }
        st4s(&r[(size_t)(ty0 + ii) * W + tx0 + c0], rv4);
#pragma unroll
        for (int k = 0; k < 4; ++k) atomicAdd(&lh[fmap(prv[k]) >> 24], 1u);
    }
    __syncthreads();
    if (tl < 256 && lh[tl]) atomicAdd(&hist1[tl], lh[tl]);
}

// ---------------- median radix-select chain (unchanged from passing R2) ----------------
__global__ __launch_bounds__(256) void k_scan256(const unsigned* __restrict__ hist,
                                                 unsigned* __restrict__ sel,
                                                 int in_rank_idx, int out_base) {
    __shared__ unsigned s[256];
    int t = threadIdx.x;
    unsigned c = hist[t];
    s[t] = c;
    __syncthreads();
    for (int off = 1; off < 256; off <<= 1) {
        unsigned v = (t >= off) ? s[t - off] : 0u;
        __syncthreads();
        s[t] += v;
        __syncthreads();
    }
    unsigned k = (in_rank_idx < 0) ? KSEL : sel[in_rank_idx];
    unsigned cumb = s[t] - c;
    if (k >= cumb && k < s[t]) {
        sel[out_base] = (unsigned)t;
        sel[out_base + 1] = k - cumb;
    }
}

__global__ __launch_bounds__(256) void k_hist2(const float* __restrict__ r,
                                               const unsigned* __restrict__ sel,
                                               unsigned* __restrict__ hist2) {
    __shared__ unsigned lh[256];
    lh[threadIdx.x] = 0;
    __syncthreads();
    unsigned b1 = sel[0];
    int idx = blockIdx.x * blockDim.x + threadIdx.x;
    int stride = gridDim.x * blockDim.x;
    const float4* r4 = (const float4*)r;
    for (int i = idx; i < NPIX / 4; i += stride) {
        float4 v = r4[i];
        unsigned u;
        u = fmap(v.x); if ((u >> 24) == b1) atomicAdd(&lh[(u >> 16) & 0xFF], 1u);
        u = fmap(v.y); if ((u >> 24) == b1) atomicAdd(&lh[(u >> 16) & 0xFF], 1u);
        u = fmap(v.z); if ((u >> 24) == b1) atomicAdd(&lh[(u >> 16) & 0xFF], 1u);
        u = fmap(v.w); if ((u >> 24) == b1) atomicAdd(&lh[(u >> 16) & 0xFF], 1u);
    }
    __syncthreads();
    if (lh[threadIdx.x]) atomicAdd(&hist2[threadIdx.x], lh[threadIdx.x]);
}

__global__ __launch_bounds__(256) void k_hist3(const float* __restrict__ r,
                                               const unsigned* __restrict__ sel,
                                               unsigned* __restrict__ hist3) {
    unsigned top16 = (sel[0] << 8) | sel[2];
    int idx = blockIdx.x * blockDim.x + threadIdx.x;
    int stride = gridDim.x * blockDim.x;
    const float4* r4 = (const float4*)r;
    for (int i = idx; i < NPIX / 4; i += stride) {
        float4 v = r4[i];
        unsigned u;
        u = fmap(v.x); if ((u >> 16) == top16) atomicAdd(&hist3[u & 0xFFFF], 1u);
        u = fmap(v.y); if ((u >> 16) == top16) atomicAdd(&hist3[u & 0xFFFF], 1u);
        u = fmap(v.z); if ((u >> 16) == top16) atomicAdd(&hist3[u & 0xFFFF], 1u);
        u = fmap(v.w); if ((u >> 16) == top16) atomicAdd(&hist3[u & 0xFFFF], 1u);
    }
}

__global__ __launch_bounds__(256) void k_scan64k(const unsigned* __restrict__ hist3,
                                                 unsigned* __restrict__ sel) {
    __shared__ unsigned s[256];
    int t = threadIdx.x;
    unsigned sum = 0;
    for (int i = 0; i < 256; ++i) sum += hist3[t * 256 + i];
    s[t] = sum;
    __syncthreads();
    for (int off = 1; off < 256; off <<= 1) {
        unsigned v = (t >= off) ? s[t - off] : 0u;
        __syncthreads();
        s[t] += v;
        __syncthreads();
    }
    unsigned k = sel[3];
    unsigned cumb = s[t] - sum;
    if (k >= cumb && k < s[t]) {
        unsigned rem = k - cumb;
        unsigned cum = 0, b3 = 0;
        for (int i = 0; i < 256; ++i) {
            unsigned c = hist3[t * 256 + i];
            if (rem < cum + c) { b3 = (unsigned)(t * 256 + i); break; }
            cum += c;
        }
        unsigned med_u = (sel[0] << 24) | (sel[2] << 16) | b3;
        unsigned bits = (med_u & 0x80000000u) ? (med_u & 0x7FFFFFFFu) : ~med_u;
        ((float*)sel)[4] = __uint_as_float(bits);
    }
}

// ---------------- Pass D: threshold + separable 7x7 maxpool + NMS ----------------
// LDS: rt[38][76] @0, th[38][76] @2888, hm[38][68] @5776  (floats; 33.4 KB)
#define RTA(r,c) smem[(r)*76 + (c)]
#define THA(r,c) smem[2888 + (r)*76 + (c)]
#define HMA(r,c) smem[5776 + (r)*68 + (c)]

__global__ __launch_bounds__(NT) void k_final(const float* __restrict__ r,
                                              const unsigned* __restrict__ sel,
                                              float* __restrict__ out) {
    __shared__ float smem[8360];
    float med = ((const float*)sel)[4];
    int tl = threadIdx.x;
    int bx = blockIdx.x & (NBX - 1);
    int by = blockIdx.x >> 6;
    int tx0 = bx * TSX, ty0 = by * TSY;
    const float NINF = -INFINITY;

    // load r tile: rows ty0-3..ty0+34 (38), cols tx0-4..tx0+67 (72 slots; halo 4 for alignment)
#pragma unroll
    for (int it = 0; it < 2; ++it) {
        int task = tl + it * NT;
        if (task < 684) {
            int row = task / 18, g = task - row * 18;
            int gy = ty0 - 3 + row;
            int gx0 = tx0 - 4 + 4 * g;
            float4 v = make_float4(NINF, NINF, NINF, NINF);
            float4 tv = v;
            float* pv = (float*)&v; float* ptv = (float*)&tv;
            if ((unsigned)gy < H) {
                if ((unsigned)gx0 <= (unsigned)(W - 4)) {
                    v = *(const float4*)&r[(size_t)gy * W + gx0];
#pragma unroll
                    for (int k = 0; k < 4; ++k) ptv[k] = (pv[k] > med) ? pv[k] : 0.f;
                } else {
#pragma unroll
                    for (int k = 0; k < 4; ++k) {
                        int c = gx0 + k;
                        if ((unsigned)c < W) {
                            float rv = r[(size_t)gy * W + c];
                            pv[k] = rv;
                            ptv[k] = (rv > med) ? rv : 0.f;
                        }
                    }
                }
            }
            st4s(&RTA(row, 4 * g), v);
            st4s(&THA(row, 4 * g), tv);
        }
    }
    __syncthreads();

    // horizontal max over 7 (th col s <-> img col tx0-4+s; out col c uses s=c+1..c+7)
#pragma unroll
    for (int it = 0; it < 2; ++it) {
        int task = tl + it * NT;
        if (task < 608) {
            int row = task >> 4, c0 = (task & 15) * 4;
            float w[12];
            {
                float4 t0 = ld4s(&THA(row, c0)), t1 = ld4s(&THA(row, c0 + 4)), t2 = ld4s(&THA(row, c0 + 8));
                w[0]=t0.x; w[1]=t0.y; w[2]=t0.z; w[3]=t0.w; w[4]=t1.x; w[5]=t1.y; w[6]=t1.z; w[7]=t1.w;
                w[8]=t2.x; w[9]=t2.y; w[10]=t2.z; w[11]=t2.w;
            }
            float4 m4;
            float* pm = (float*)&m4;
#pragma unroll
            for (int k = 0; k < 4; ++k) {
                float m = w[k + 1];
#pragma unroll
                for (int b = 2; b < 8; ++b) m = fmaxf(m, w[k + b]);
                pm[k] = m;
            }
            st4s(&HMA(row, c0), m4);
        }
    }
    __syncthreads();

    // vertical max over 7 + NMS + output
    {
        int ii = tl >> 4, c0 = (tl & 15) * 4;
        float4 m = ld4s(&HMA(ii, c0));
#pragma unroll
        for (int a = 1; a < 7; ++a) {
            float4 h = ld4s(&HMA(ii + a, c0));
            m.x = fmaxf(m.x, h.x); m.y = fmaxf(m.y, h.y);
            m.z = fmaxf(m.z, h.z); m.w = fmaxf(m.w, h.w);
        }
        float4 rv = ld4s(&RTA(ii + 3, c0 + 4));
        float4 tv = ld4s(&THA(ii + 3, c0 + 4));
        float4 o;
        o.x = (m.x == tv.x) ? rv.x : 0.f;
        o.y = (m.y == tv.y) ? rv.y : 0.f;
        o.z = (m.z == tv.z) ? rv.z : 0.f;
        o.w = (m.w == tv.w) ? rv.w : 0.f;
        st4s(&out[(size_t)(ty0 + ii) * W + tx0 + c0], o);
    }
}

extern "C" void kernel_launch(void* const* d_in, const int* in_sizes, int n_in,
                              void* d_out, int out_size, void* d_ws, size_t ws_size,
                              hipStream_t stream) {
    const float* x = (const float*)d_in[0];
    const float* gw = (const float*)d_in[2];
    float* out = (float*)d_out;

    char* ws = (char*)d_ws;
    float* r = (float*)ws;
    unsigned* hist1 = (unsigned*)(ws + (size_t)NPIX * 4);
    unsigned* hist2 = hist1 + 256;
    unsigned* hist3 = hist2 + 256;
    unsigned* sel = hist3 + 65536;

    hipMemsetAsync(hist1, 0, (256 + 256 + 65536 + 8) * sizeof(unsigned), stream);

    int nblk = NBX * NBY; // 64 * 64 = 4096
    k_response<<<nblk, NT, 0, stream>>>(x, gw, r, hist1);
    k_scan256<<<1, 256, 0, stream>>>(hist1, sel, -1, 0);
    k_hist2<<<1024, 256, 0, stream>>>(r, sel, hist2);
    k_scan256<<<1, 256, 0, stream>>>(hist2, sel, 1, 2);
    k_hist3<<<1024, 256, 0, stream>>>(r, sel, hist3);
    k_scan64k<<<1, 256, 0, stream>>>(hist3, sel);
    k_final<<<nblk, NT, 0, stream>>>(r, sel, out);
}